// Round 5
// baseline (27.429 us; speedup 1.0000x reference)
//
#include <hip/hip_runtime.h>

#define CHUNK 6
#define BLK 512

// d_ws layout: [0..3] int ticket; [16...] float partials SoA p0[nb],p1[nb],p2[nb]
__global__ void ticket_init_kernel(int* __restrict__ ticket) {
    *ticket = 0;
}

// Single main kernel: coalesced float4 streams for resnet/y/avg, LDS-staged
// gru chunks, block reduce, last-block election via release/acquire ticket,
// elected block reduces partials (plain L2 loads) and finalizes in double.
__global__ __launch_bounds__(BLK) void loss_onepass_kernel(
    const float* __restrict__ resnet, const float* __restrict__ gru,
    const float* __restrict__ avgp,   const float* __restrict__ y,
    const float* __restrict__ avgh,
    int* __restrict__ ticket, float* __restrict__ partials,
    int nb, int C, int M, int N, float* __restrict__ out)
{
    const int tid = threadIdx.x;
    const int gid = blockIdx.x * BLK + tid;
    const int T   = nb * BLK;

    float s_l1a = 0.f, s_l1b = 0.f, s_sm = 0.f;

    // ---- resnet vs y: lane-contiguous float4 grid-stride (perfect coalescing)
    const int Nv4 = N >> 2;
    const float4* r4 = reinterpret_cast<const float4*>(resnet);
    const float4* y4 = reinterpret_cast<const float4*>(y);
    for (int i = gid; i < Nv4; i += T) {
        float4 r = r4[i], v = y4[i];
        s_l1a += fabsf(r.x - v.x) + fabsf(r.y - v.y)
               + fabsf(r.z - v.z) + fabsf(r.w - v.w);
    }

    // ---- average streams: lane-contiguous float4
    const int Mv4 = M >> 2;
    const float4* ap4 = reinterpret_cast<const float4*>(avgp);
    const float4* ah4 = reinterpret_cast<const float4*>(avgh);
    for (int i = gid; i < Mv4; i += T) {
        float4 p = ap4[i], h = ah4[i];
        s_l1b += fabsf(p.x - h.x) + fabsf(p.y - h.y)
               + fabsf(p.z - h.z) + fabsf(p.w - h.w);
    }

    // scalar tails (empty at this problem's sizes)
    if (gid == 0) {
        for (int k = Nv4 << 2; k < N; ++k) s_l1a += fabsf(resnet[k] - y[k]);
        for (int k = Mv4 << 2; k < M; ++k) s_l1b += fabsf(avgp[k] - avgh[k]);
        if (C & 1) {
            int base = CHUNK * (C - 1);
            float x0=gru[base],x1=gru[base+1],x2=gru[base+2];
            float x3=gru[base+3],x4=gru[base+4],x5=gru[base+5];
            float m = (x0+x1+x2+x3+x4+x5) * (1.0f/6.0f);
            s_sm += fabsf(x0-m)+fabsf(x1-m)+fabsf(x2-m)
                  + fabsf(x3-m)+fabsf(x4-m)+fabsf(x5-m);
        }
    }

    // ---- gru smoothness: LDS-staged. Coalesced float4 loads in, contiguous
    // 48B chunk-pair reads out. Pair i = gru float4s [3i,3i+3) = chunks 2i,2i+1.
    __shared__ float4 lds4[BLK * 3];          // 24 KiB
    const int Cp = C >> 1;
    const float4* g4 = reinterpret_cast<const float4*>(gru);
    for (int base = blockIdx.x * BLK; base < Cp; base += T) {
        int np  = min(BLK, Cp - base);
        int nf4 = np * 3;
        for (int j = tid; j < nf4; j += BLK) lds4[j] = g4[base * 3 + j];
        __syncthreads();
        if (tid < np) {
            float4 ga = lds4[3*tid], gb = lds4[3*tid+1], gc = lds4[3*tid+2];
            float mA = (ga.x + ga.y + ga.z + ga.w + gb.x + gb.y) * (1.0f/6.0f);
            float mB = (gb.z + gb.w + gc.x + gc.y + gc.z + gc.w) * (1.0f/6.0f);
            s_sm += fabsf(ga.x-mA)+fabsf(ga.y-mA)+fabsf(ga.z-mA)+fabsf(ga.w-mA)
                  + fabsf(gb.x-mA)+fabsf(gb.y-mA)
                  + fabsf(gb.z-mB)+fabsf(gb.w-mB)
                  + fabsf(gc.x-mB)+fabsf(gc.y-mB)+fabsf(gc.z-mB)+fabsf(gc.w-mB);
        }
        __syncthreads();
    }

    // ---- block reduction
    #pragma unroll
    for (int off = 32; off > 0; off >>= 1) {
        s_l1a += __shfl_down(s_l1a, off, 64);
        s_l1b += __shfl_down(s_l1b, off, 64);
        s_sm  += __shfl_down(s_sm,  off, 64);
    }
    __shared__ float red0[8], red1[8], red2[8];   // 512 thr = 8 waves
    int wave = tid >> 6, lane = tid & 63;
    if (lane == 0) { red0[wave] = s_l1a; red1[wave] = s_l1b; red2[wave] = s_sm; }
    __syncthreads();

    __shared__ bool s_last;
    if (tid == 0) {
        float p0 = 0.f, p1 = 0.f, p2 = 0.f;
        #pragma unroll
        for (int w = 0; w < 8; ++w) { p0 += red0[w]; p1 += red1[w]; p2 += red2[w]; }
        partials[blockIdx.x]          = p0;   // plain stores, released by the
        partials[nb + blockIdx.x]     = p1;   // acq_rel RMW below (release seq
        partials[2 * nb + blockIdx.x] = p2;   // through the ticket RMW chain)
        int old = __hip_atomic_fetch_add(ticket, 1, __ATOMIC_ACQ_REL,
                                         __HIP_MEMORY_SCOPE_AGENT);
        s_last = (old == nb - 1);
    }
    __syncthreads();

    // ---- elected last block: reduce partials in double, finalize
    if (s_last) {
        double a = 0.0, b = 0.0, c = 0.0;
        for (int i = tid; i < nb; i += BLK) {
            a += (double)partials[i];
            b += (double)partials[nb + i];
            c += (double)partials[2 * nb + i];
        }
        #pragma unroll
        for (int off = 32; off > 0; off >>= 1) {
            a += __shfl_down(a, off, 64);
            b += __shfl_down(b, off, 64);
            c += __shfl_down(c, off, 64);
        }
        __shared__ double ra[8], rb[8], rc[8];
        if (lane == 0) { ra[wave] = a; rb[wave] = b; rc[wave] = c; }
        __syncthreads();
        if (tid == 0) {
            double sa = 0.0, sb = 0.0, sc = 0.0;
            #pragma unroll
            for (int w = 0; w < 8; ++w) { sa += ra[w]; sb += rb[w]; sc += rc[w]; }
            double l1     = sa / (double)N + sb / (double)M;
            double smooth = sc / (double)CHUNK;
            double total  = l1 + 100.0 * smooth;
            out[0] = (float)total;
            out[1] = (float)l1;
            out[2] = (float)smooth;
        }
    }
}

extern "C" void kernel_launch(void* const* d_in, const int* in_sizes, int n_in,
                              void* d_out, int out_size, void* d_ws, size_t ws_size,
                              hipStream_t stream) {
    const float* resnet = (const float*)d_in[0];
    const float* gru    = (const float*)d_in[1];
    const float* avgp   = (const float*)d_in[2];
    const float* y      = (const float*)d_in[3];
    const float* avgh   = (const float*)d_in[4];
    float* out = (float*)d_out;

    int N = in_sizes[0];          // 3,000,000
    int M = in_sizes[2];          // 500,000
    int C = N / CHUNK;            // 500,000 chunks

    int Cp = C >> 1;
    int work = (Cp > (M >> 2)) ? Cp : (M >> 2);
    if (work < 1) work = 1;
    int nb = (work + BLK - 1) / BLK;          // ~489 blocks

    int*   ticket   = (int*)d_ws;
    float* partials = (float*)((char*)d_ws + 16);

    ticket_init_kernel<<<1, 1, 0, stream>>>(ticket);
    loss_onepass_kernel<<<nb, BLK, 0, stream>>>(resnet, gru, avgp, y, avgh,
                                                ticket, partials, nb, C, M, N, out);
}

// Round 6
// 13.720 us; speedup vs baseline: 1.9992x; 1.9992x over previous
//
#include <hip/hip_runtime.h>

#define CHUNK 6
#define BLK 256

// Stage 1: chunk-QUAD per thread. gru: 6 consecutive float4s (96B, 4 chunks).
// resnet/y/avg: fully coalesced float4 grid-stride (no chunk structure needed).
// One partial triple per block -> d_ws (SoA). No atomics anywhere.
__global__ __launch_bounds__(BLK) void loss_partial_kernel(
    const float* __restrict__ resnet, const float* __restrict__ gru,
    const float* __restrict__ avgp,   const float* __restrict__ y,
    const float* __restrict__ avgh,
    float* __restrict__ partials, int nb, int C, int M, int N)
{
    const int tid = threadIdx.x;
    const int gid = blockIdx.x * BLK + tid;
    const int T   = nb * BLK;

    float s_l1a = 0.f, s_l1b = 0.f, s_sm = 0.f;

    // ---- gru quad: issue all 6 loads up front (MLP), compute later
    const int Cq = C >> 2;                       // chunk quads
    const float4* g4 = reinterpret_cast<const float4*>(gru);
    float4 q0, q1, q2, q3, q4, q5;
    const bool have_q = (gid < Cq);
    if (have_q) {
        const float4* p = g4 + 6 * gid;
        q0 = p[0]; q1 = p[1]; q2 = p[2]; q3 = p[3]; q4 = p[4]; q5 = p[5];
    }

    // ---- avg: one coalesced float4 (Mv4 == thread count here)
    const int Mv4 = M >> 2;
    if (gid < Mv4) {
        float4 p = reinterpret_cast<const float4*>(avgp)[gid];
        float4 h = reinterpret_cast<const float4*>(avgh)[gid];
        s_l1b = fabsf(p.x - h.x) + fabsf(p.y - h.y)
              + fabsf(p.z - h.z) + fabsf(p.w - h.w);
    }

    // ---- resnet vs y: coalesced float4 grid-stride (~6 iters)
    const int Nv4 = N >> 2;
    const float4* r4 = reinterpret_cast<const float4*>(resnet);
    const float4* y4 = reinterpret_cast<const float4*>(y);
    for (int i = gid; i < Nv4; i += T) {
        float4 r = r4[i], v = y4[i];
        s_l1a += fabsf(r.x - v.x) + fabsf(r.y - v.y)
               + fabsf(r.z - v.z) + fabsf(r.w - v.w);
    }

    // ---- gru smoothness compute (loads long since landed)
    if (have_q) {
        // chunk0 = q0.xyzw q1.xy | chunk1 = q1.zw q2.xyzw
        // chunk2 = q3.xyzw q4.xy | chunk3 = q4.zw q5.xyzw
        float m0 = (q0.x + q0.y + q0.z + q0.w + q1.x + q1.y) * (1.0f / 6.0f);
        float m1 = (q1.z + q1.w + q2.x + q2.y + q2.z + q2.w) * (1.0f / 6.0f);
        float m2 = (q3.x + q3.y + q3.z + q3.w + q4.x + q4.y) * (1.0f / 6.0f);
        float m3 = (q4.z + q4.w + q5.x + q5.y + q5.z + q5.w) * (1.0f / 6.0f);
        s_sm = fabsf(q0.x-m0)+fabsf(q0.y-m0)+fabsf(q0.z-m0)+fabsf(q0.w-m0)
             + fabsf(q1.x-m0)+fabsf(q1.y-m0)
             + fabsf(q1.z-m1)+fabsf(q1.w-m1)
             + fabsf(q2.x-m1)+fabsf(q2.y-m1)+fabsf(q2.z-m1)+fabsf(q2.w-m1)
             + fabsf(q3.x-m2)+fabsf(q3.y-m2)+fabsf(q3.z-m2)+fabsf(q3.w-m2)
             + fabsf(q4.x-m2)+fabsf(q4.y-m2)
             + fabsf(q4.z-m3)+fabsf(q4.w-m3)
             + fabsf(q5.x-m3)+fabsf(q5.y-m3)+fabsf(q5.z-m3)+fabsf(q5.w-m3);
    }

    // ---- scalar tails (empty at this problem's sizes)
    if (gid == 0) {
        for (int k = Nv4 << 2; k < N; ++k) s_l1a += fabsf(resnet[k] - y[k]);
        for (int k = Mv4 << 2; k < M; ++k) s_l1b += fabsf(avgp[k] - avgh[k]);
        for (int c = Cq << 2; c < C; ++c) {
            int base = CHUNK * c;
            float x0=gru[base],x1=gru[base+1],x2=gru[base+2];
            float x3=gru[base+3],x4=gru[base+4],x5=gru[base+5];
            float m = (x0+x1+x2+x3+x4+x5) * (1.0f/6.0f);
            s_sm += fabsf(x0-m)+fabsf(x1-m)+fabsf(x2-m)
                  + fabsf(x3-m)+fabsf(x4-m)+fabsf(x5-m);
        }
    }

    // ---- block reduction: wave shuffle + 4-wave LDS
    #pragma unroll
    for (int off = 32; off > 0; off >>= 1) {
        s_l1a += __shfl_down(s_l1a, off, 64);
        s_l1b += __shfl_down(s_l1b, off, 64);
        s_sm  += __shfl_down(s_sm,  off, 64);
    }
    __shared__ float red0[4], red1[4], red2[4];
    int wave = tid >> 6, lane = tid & 63;
    if (lane == 0) { red0[wave] = s_l1a; red1[wave] = s_l1b; red2[wave] = s_sm; }
    __syncthreads();

    if (tid == 0) {
        partials[blockIdx.x]          = red0[0] + red0[1] + red0[2] + red0[3];
        partials[nb + blockIdx.x]     = red1[0] + red1[1] + red1[2] + red1[3];
        partials[2 * nb + blockIdx.x] = red2[0] + red2[1] + red2[2] + red2[3];
    }
}

// Stage 2: one 256-thread block reduces nb partial triples (double) + finalizes.
__global__ __launch_bounds__(256) void loss_reduce_kernel(
    const float* __restrict__ partials, int nb,
    float* __restrict__ out, int N, int M)
{
    double a = 0.0, b = 0.0, c = 0.0;
    for (int i = threadIdx.x; i < nb; i += 256) {
        a += (double)partials[i];
        b += (double)partials[nb + i];
        c += (double)partials[2 * nb + i];
    }
    #pragma unroll
    for (int off = 32; off > 0; off >>= 1) {
        a += __shfl_down(a, off, 64);
        b += __shfl_down(b, off, 64);
        c += __shfl_down(c, off, 64);
    }
    __shared__ double ra[4], rb[4], rc[4];
    int wave = threadIdx.x >> 6, lane = threadIdx.x & 63;
    if (lane == 0) { ra[wave] = a; rb[wave] = b; rc[wave] = c; }
    __syncthreads();

    if (threadIdx.x == 0) {
        double sa = ra[0] + ra[1] + ra[2] + ra[3];
        double sb = rb[0] + rb[1] + rb[2] + rb[3];
        double sc = rc[0] + rc[1] + rc[2] + rc[3];
        double l1     = sa / (double)N + sb / (double)M;
        double smooth = sc / (double)CHUNK;
        double total  = l1 + 100.0 * smooth;
        out[0] = (float)total;
        out[1] = (float)l1;
        out[2] = (float)smooth;
    }
}

extern "C" void kernel_launch(void* const* d_in, const int* in_sizes, int n_in,
                              void* d_out, int out_size, void* d_ws, size_t ws_size,
                              hipStream_t stream) {
    const float* resnet = (const float*)d_in[0];
    const float* gru    = (const float*)d_in[1];
    const float* avgp   = (const float*)d_in[2];
    const float* y      = (const float*)d_in[3];
    const float* avgh   = (const float*)d_in[4];
    float* out = (float*)d_out;

    int N = in_sizes[0];          // 3,000,000
    int M = in_sizes[2];          // 500,000
    int C = N / CHUNK;            // 500,000 chunks

    int Cq  = C >> 2;             // 125,000 quads
    int Mv4 = M >> 2;             // 125,000 float4s
    int work = (Cq > Mv4) ? Cq : Mv4;
    if (work < 1) work = 1;
    int nb = (work + BLK - 1) / BLK;          // 489 blocks

    float* partials = (float*)d_ws;           // 3 * nb floats

    loss_partial_kernel<<<nb, BLK, 0, stream>>>(resnet, gru, avgp, y, avgh,
                                                partials, nb, C, M, N);
    loss_reduce_kernel<<<1, 256, 0, stream>>>(partials, nb, out, N, M);
}